// Round 1
// baseline (903.751 us; speedup 1.0000x reference)
//
#include <hip/hip_runtime.h>

#define B_ 2
#define L_ 2048
#define H_ 8
#define E_ 64

typedef __attribute__((ext_vector_type(8))) short short8;
typedef __attribute__((ext_vector_type(4))) float f32x4;

static constexpr size_t OFF_S = 2097152;            // B*L*H*D
static constexpr size_t OFF_P = OFF_S + 67108864;   // + B*H*L*L
static constexpr size_t OFF_G = OFF_P + 67108864;

__device__ __forceinline__ unsigned short f2bf(float x) {
    union { float f; unsigned int u; } c; c.f = x;
    unsigned int u = c.u;
    u += 0x7fffu + ((u >> 16) & 1u);               // RNE
    return (unsigned short)(u >> 16);
}

__device__ __forceinline__ void st_bf4(unsigned short* dst, float4 x) {
    union { unsigned short u[4]; uint2 v; } t;
    t.u[0] = f2bf(x.x); t.u[1] = f2bf(x.y); t.u[2] = f2bf(x.z); t.u[3] = f2bf(x.w);
    *reinterpret_cast<uint2*>(dst) = t.v;          // 8B aligned (col multiple of 4)
}

// One block = 16 query rows ("strip") of one (b,h). Grid = 128 strips * 16 bh = 2048.
__global__ __launch_bounds__(256) void attn_all(
    const float* __restrict__ q, const float* __restrict__ k,
    const float* __restrict__ v, const float* __restrict__ sg,
    float* __restrict__ out)
{
    // padded rows: 72 bf16 = 144 B -> 16B-aligned b128 frag reads, 4-bank rotation
    __shared__ __attribute__((aligned(16))) unsigned short Ks[64][72];
    __shared__ __attribute__((aligned(16))) unsigned short Vt[64][72];
    __shared__ __attribute__((aligned(16))) unsigned short Pt[16][72];
    __shared__ float l_sums[16];
    __shared__ float rowA[16], rowC[16], rowSig[16];

    const int tid  = threadIdx.x;
    const int wv   = tid >> 6;
    const int lane = tid & 63;
    const int quad = lane >> 4;
    const int l16  = lane & 15;

    const int blk = blockIdx.x;
    const int s   = 127 - (blk >> 4);   // heavy strips first
    const int bh  = blk & 15;
    const int b   = bh >> 3;
    const int h   = bh & 7;
    const int i0  = s << 4;

    if (tid < 16) l_sums[tid] = 0.0f;

    // ---- Q fragments (A operand, held in regs): m = lane&15, k = 32*step + quad*8 + j
    short8 a0, a1;
    {
        const float* qr = q + ((size_t)((b * L_ + (i0 + l16)) * H_ + h)) * E_;
        const float4* q4 = reinterpret_cast<const float4*>(qr) + quad * 2;
        float4 x0 = q4[0], x1 = q4[1];       // k = quad*8 .. quad*8+7
        float4 y0 = q4[8], y1 = q4[9];       // k = 32+quad*8 ..
        union { short8 v8; unsigned short u[8]; } fa, fb;
        fa.u[0]=f2bf(x0.x); fa.u[1]=f2bf(x0.y); fa.u[2]=f2bf(x0.z); fa.u[3]=f2bf(x0.w);
        fa.u[4]=f2bf(x1.x); fa.u[5]=f2bf(x1.y); fa.u[6]=f2bf(x1.z); fa.u[7]=f2bf(x1.w);
        fb.u[0]=f2bf(y0.x); fb.u[1]=f2bf(y0.y); fb.u[2]=f2bf(y0.z); fb.u[3]=f2bf(y0.w);
        fb.u[4]=f2bf(y1.x); fb.u[5]=f2bf(y1.y); fb.u[6]=f2bf(y1.z); fb.u[7]=f2bf(y1.w);
        a0 = fa.v8; a1 = fb.v8;
    }

    const int ntiles = ((i0 + 15) >> 6) + 1;
    const int jend   = ntiles << 6;          // <= 2048

    // =========================== PASS A: row sums ===========================
    float lpart[4] = {0.f, 0.f, 0.f, 0.f};
    for (int t = 0; t < ntiles; ++t) {
        const int j0 = t << 6;
        __syncthreads();                     // Ks safe to overwrite
        {
            int r = tid >> 4;
            const int c = (tid & 15) << 2;
            #pragma unroll
            for (int p = 0; p < 4; ++p, r += 16) {
                const size_t g = ((size_t)((b * L_ + (j0 + r)) * H_ + h)) * E_ + c;
                st_bf4(&Ks[r][c], *reinterpret_cast<const float4*>(k + g));
            }
        }
        __syncthreads();
        const unsigned short* krow = &Ks[(wv << 4) + l16][0];
        short8 b0 = *reinterpret_cast<const short8*>(krow + quad * 8);
        short8 b1 = *reinterpret_cast<const short8*>(krow + 32 + quad * 8);
        f32x4 c4 = {0.f, 0.f, 0.f, 0.f};
        c4 = __builtin_amdgcn_mfma_f32_16x16x32_bf16(a0, b0, c4, 0, 0, 0);
        c4 = __builtin_amdgcn_mfma_f32_16x16x32_bf16(a1, b1, c4, 0, 0, 0);
        const int j = j0 + (wv << 4) + l16;
        #pragma unroll
        for (int r = 0; r < 4; ++r) {
            const int i = i0 + (quad << 2) + r;
            // fixed-shift softmax: exp(s-8), shift cancels in normalization
            lpart[r] += (j <= i) ? __expf(c4[r] * 0.125f - 8.0f) : 0.0f;
        }
    }
    #pragma unroll
    for (int r = 0; r < 4; ++r) {
        float x = lpart[r];
        x += __shfl_xor(x, 1); x += __shfl_xor(x, 2);
        x += __shfl_xor(x, 4); x += __shfl_xor(x, 8);
        if (l16 == 0) atomicAdd(&l_sums[(quad << 2) + r], x);
    }
    __syncthreads();
    float inv[4];
    #pragma unroll
    for (int r = 0; r < 4; ++r) inv[r] = 1.0f / l_sums[(quad << 2) + r];

    // ================= PASS B: series writes + PV via MFMA =================
    f32x4 oacc = {0.f, 0.f, 0.f, 0.f};
    float* outS = out + OFF_S;
    for (int t = 0; t < ntiles; ++t) {
        const int j0 = t << 6;
        __syncthreads();                     // Ks/Vt/Pt safe to overwrite
        {
            int r = tid >> 4;
            const int c = (tid & 15) << 2;
            #pragma unroll
            for (int p = 0; p < 4; ++p, r += 16) {
                const size_t g = ((size_t)((b * L_ + (j0 + r)) * H_ + h)) * E_ + c;
                st_bf4(&Ks[r][c], *reinterpret_cast<const float4*>(k + g));
                const float4 vv = *reinterpret_cast<const float4*>(v + g);
                Vt[c + 0][r] = f2bf(vv.x);   // transposed stage for B-operand reads
                Vt[c + 1][r] = f2bf(vv.y);
                Vt[c + 2][r] = f2bf(vv.z);
                Vt[c + 3][r] = f2bf(vv.w);
            }
        }
        __syncthreads();
        const unsigned short* krow = &Ks[(wv << 4) + l16][0];
        short8 b0 = *reinterpret_cast<const short8*>(krow + quad * 8);
        short8 b1 = *reinterpret_cast<const short8*>(krow + 32 + quad * 8);
        f32x4 c4 = {0.f, 0.f, 0.f, 0.f};
        c4 = __builtin_amdgcn_mfma_f32_16x16x32_bf16(a0, b0, c4, 0, 0, 0);
        c4 = __builtin_amdgcn_mfma_f32_16x16x32_bf16(a1, b1, c4, 0, 0, 0);
        const int j = j0 + (wv << 4) + l16;
        #pragma unroll
        for (int r = 0; r < 4; ++r) {
            const int i = i0 + (quad << 2) + r;
            float p = (j <= i) ? __expf(c4[r] * 0.125f - 8.0f) : 0.0f;
            float pn = p * inv[r];
            outS[((size_t)bh * L_ + i) * L_ + j] = pn;
            Pt[(quad << 2) + r][(wv << 4) + l16] = f2bf(pn);   // C-layout -> A-layout via LDS
        }
        __syncthreads();
        const unsigned short* prow = &Pt[l16][0];
        const unsigned short* vrow = &Vt[(wv << 4) + l16][0];
        short8 pa0 = *reinterpret_cast<const short8*>(prow + quad * 8);
        short8 pa1 = *reinterpret_cast<const short8*>(prow + 32 + quad * 8);
        short8 vb0 = *reinterpret_cast<const short8*>(vrow + quad * 8);
        short8 vb1 = *reinterpret_cast<const short8*>(vrow + 32 + quad * 8);
        oacc = __builtin_amdgcn_mfma_f32_16x16x32_bf16(pa0, vb0, oacc, 0, 0, 0);
        oacc = __builtin_amdgcn_mfma_f32_16x16x32_bf16(pa1, vb1, oacc, 0, 0, 0);
    }
    // V output (normalized P used, so no rescale)
    #pragma unroll
    for (int r = 0; r < 4; ++r) {
        const int i = i0 + (quad << 2) + r;
        const int d = (wv << 4) + l16;
        out[((size_t)((b * L_ + i) * H_ + h)) * 64 + d] = oacc[r];
    }

    // ============ PHASE C: prior + sigma_out + series zero-fill ============
    __syncthreads();
    if (tid < 16) {
        const int i = i0 + tid;
        const float x   = sg[(size_t)(b * L_ + i) * H_ + h];
        const float sgm = 1.0f / (1.0f + __expf(-5.0f * x)) + 1e-5f;
        const float sp  = expm1f(sgm * 1.0986122886681098f);   // 3^sgm - 1, no cancellation
        rowSig[tid] = sp;
        rowA[tid]   = 0.3989422804014327f / sp;                // 1/sqrt(2pi)/sig
        rowC[tid]   = 0.5f / (sp * sp);
    }
    __syncthreads();
    float* outP = out + OFF_P;
    float* outG = out + OFF_G;
    for (int r = 0; r < 16; ++r) {
        const int i = i0 + r;
        const float A  = rowA[r];
        const float C2 = rowC[r];
        const float S  = rowSig[r];
        const size_t rb = ((size_t)bh * L_ + i) * L_;
        #pragma unroll
        for (int p = 0; p < 2; ++p) {
            const int c = (tid + (p << 8)) << 2;
            const float d0 = (float)(i - c);
            const float d1 = d0 - 1.0f, d2 = d0 - 2.0f, d3 = d0 - 3.0f;
            float4 pr;
            pr.x = A * __expf(-d0 * d0 * C2);
            pr.y = A * __expf(-d1 * d1 * C2);
            pr.z = A * __expf(-d2 * d2 * C2);
            pr.w = A * __expf(-d3 * d3 * C2);
            *reinterpret_cast<float4*>(outP + rb + c) = pr;
            float4 sv = {S, S, S, S};
            *reinterpret_cast<float4*>(outG + rb + c) = sv;
            if (c >= jend) {                       // strict upper region never touched in pass B
                float4 z = {0.f, 0.f, 0.f, 0.f};
                *reinterpret_cast<float4*>(outS + rb + c) = z;
            }
        }
    }
}

extern "C" void kernel_launch(void* const* d_in, const int* in_sizes, int n_in,
                              void* d_out, int out_size, void* d_ws, size_t ws_size,
                              hipStream_t stream) {
    const float* q  = (const float*)d_in[0];
    const float* k  = (const float*)d_in[1];
    const float* v  = (const float*)d_in[2];
    const float* sg = (const float*)d_in[3];
    attn_all<<<dim3(2048), dim3(256), 0, stream>>>(q, k, v, sg, (float*)d_out);
}

// Round 2
// 892.186 us; speedup vs baseline: 1.0130x; 1.0130x over previous
//
#include <hip/hip_runtime.h>

#define L_ 2048
#define H_ 8

typedef __attribute__((ext_vector_type(8))) short short8;
typedef __attribute__((ext_vector_type(4))) float f32x4;

static constexpr size_t OFF_S = 2097152;            // B*L*H*D
static constexpr size_t OFF_P = OFF_S + 67108864;   // + B*H*L*L
static constexpr size_t OFF_G = OFF_P + 67108864;

// ws layout (bytes): inv_l at 0 (128 KB), K tiles at 1 MB (4 MB), V tiles at 5 MB (4 MB)
static constexpr size_t WS_K = 1u << 20;
static constexpr size_t WS_V = WS_K + (4u << 20);

__device__ __forceinline__ unsigned short f2bf(float x) {
    union { float f; unsigned int u; } c; c.f = x;
    unsigned int u = c.u;
    u += 0x7fffu + ((u >> 16) & 1u);               // RNE
    return (unsigned short)(u >> 16);
}
__device__ __forceinline__ float bf2f(unsigned short u) {
    union { float f; unsigned int v; } c; c.v = ((unsigned int)u) << 16; return c.f;
}

__device__ __forceinline__ void gld_lds16(const unsigned short* g, unsigned short* l) {
    __builtin_amdgcn_global_load_lds(
        (const __attribute__((address_space(1))) void*)g,
        (__attribute__((address_space(3))) void*)l, 16, 0, 0);
}

// ===== kernel 0: K -> bf16 swizzled tiles; V -> bf16 transposed swizzled tiles =====
// tile image: 64 rows x 64 bf16; element (r, chunk c) at r*64 + (c ^ (r&7))*8 shorts.
__global__ __launch_bounds__(256) void prep(
    const float* __restrict__ k, const float* __restrict__ v,
    unsigned short* __restrict__ wsK, unsigned short* __restrict__ wsV)
{
    const int tid = threadIdx.x;
    const int blk = blockIdx.x;
    __shared__ __attribute__((aligned(16))) unsigned short tr[64][72];
    if (blk < 512) {                                 // K path: (bh, t)
        const int bh = blk >> 5, t = blk & 31;
        const int b = bh >> 3, h = bh & 7;
        unsigned short* dst = wsK + (size_t)(bh * 32 + t) * 4096;
        #pragma unroll
        for (int p = 0; p < 2; ++p) {
            const int cid = tid + (p << 8);
            const int r = cid >> 3, c = cid & 7;
            const int j = (t << 6) + r;
            const float4* src = reinterpret_cast<const float4*>(
                k + (((size_t)((b * L_ + j) * H_ + h)) << 6) + (c << 3));
            float4 x0 = src[0], x1 = src[1];
            union { short8 s; unsigned short u[8]; } w;
            w.u[0]=f2bf(x0.x); w.u[1]=f2bf(x0.y); w.u[2]=f2bf(x0.z); w.u[3]=f2bf(x0.w);
            w.u[4]=f2bf(x1.x); w.u[5]=f2bf(x1.y); w.u[6]=f2bf(x1.z); w.u[7]=f2bf(x1.w);
            *reinterpret_cast<short8*>(dst + r * 64 + ((c ^ (r & 7)) << 3)) = w.s;
        }
    } else {                                         // V path: transpose via LDS
        const int vb = blk - 512;
        const int bh = vb >> 5, t = vb & 31;
        const int b = bh >> 3, h = bh & 7;
        const int col4 = (tid & 15) << 2;
        #pragma unroll
        for (int p = 0; p < 4; ++p) {
            const int r = (tid >> 4) + (p << 4);
            const int j = (t << 6) + r;
            float4 x = *reinterpret_cast<const float4*>(
                v + (((size_t)((b * L_ + j) * H_ + h)) << 6) + col4);
            tr[col4 + 0][r] = f2bf(x.x); tr[col4 + 1][r] = f2bf(x.y);
            tr[col4 + 2][r] = f2bf(x.z); tr[col4 + 3][r] = f2bf(x.w);
        }
        __syncthreads();
        unsigned short* dst = wsV + (size_t)(bh * 32 + t) * 4096;
        #pragma unroll
        for (int p = 0; p < 2; ++p) {
            const int cid = tid + (p << 8);
            const int d = cid >> 3, cj = cid & 7;
            short8 s = *reinterpret_cast<const short8*>(&tr[d][cj << 3]);
            *reinterpret_cast<short8*>(dst + d * 64 + ((cj ^ (d & 7)) << 3)) = s;
        }
    }
}

// ===== kernel 1: single-pass attention, unnormalized p out, V out, inv_l to ws =====
__global__ __launch_bounds__(256) void attn(
    const float* __restrict__ q,
    const unsigned short* __restrict__ wsK, const unsigned short* __restrict__ wsV,
    float* __restrict__ out, float* __restrict__ ws_inv)
{
    __shared__ __attribute__((aligned(16))) unsigned short Kb[2][4096];
    __shared__ __attribute__((aligned(16))) unsigned short Vb[2][4096];
    __shared__ __attribute__((aligned(16))) unsigned short Pt[16][72];
    __shared__ float l_sums[16];

    const int tid  = threadIdx.x;
    const int wv   = tid >> 6;
    const int lane = tid & 63;
    const int quad = lane >> 4;
    const int l16  = lane & 15;

    const int blk = blockIdx.x;
    const int s   = 127 - (blk >> 4);                // heavy strips first
    const int bh  = blk & 15;
    const int b   = bh >> 3, h = bh & 7;
    const int i0  = s << 4;

    if (tid < 16) l_sums[tid] = 0.0f;

    // Q A-fragments (fp32 -> bf16, once per block)
    short8 a0, a1;
    {
        const float* qr = q + (((size_t)((b * L_ + (i0 + l16)) * H_ + h)) << 6);
        const float4* q4 = reinterpret_cast<const float4*>(qr) + quad * 2;
        float4 x0 = q4[0], x1 = q4[1];
        float4 y0 = q4[8], y1 = q4[9];
        union { short8 v8; unsigned short u[8]; } fa, fb;
        fa.u[0]=f2bf(x0.x); fa.u[1]=f2bf(x0.y); fa.u[2]=f2bf(x0.z); fa.u[3]=f2bf(x0.w);
        fa.u[4]=f2bf(x1.x); fa.u[5]=f2bf(x1.y); fa.u[6]=f2bf(x1.z); fa.u[7]=f2bf(x1.w);
        fb.u[0]=f2bf(y0.x); fb.u[1]=f2bf(y0.y); fb.u[2]=f2bf(y0.z); fb.u[3]=f2bf(y0.w);
        fb.u[4]=f2bf(y1.x); fb.u[5]=f2bf(y1.y); fb.u[6]=f2bf(y1.z); fb.u[7]=f2bf(y1.w);
        a0 = fa.v8; a1 = fb.v8;
    }

    const int ntiles = (s >> 2) + 1;
    const unsigned short* gK = wsK + ((size_t)bh * 32) * 4096;
    const unsigned short* gV = wsV + ((size_t)bh * 32) * 4096;

    // stage tile t into buffer buf: each wave DMAs its 2 KB of K and V (2x 1KB each)
    #define STAGE(buf, t) do {                                              \
        const unsigned short* _sk = gK + (size_t)(t) * 4096;                \
        const unsigned short* _sv = gV + (size_t)(t) * 4096;                \
        _Pragma("unroll")                                                   \
        for (int _qq = 0; _qq < 2; ++_qq) {                                 \
            const int _off = (wv << 10) + (_qq << 9);                       \
            gld_lds16(_sk + _off + (lane << 3), &Kb[buf][_off]);            \
            gld_lds16(_sv + _off + (lane << 3), &Vb[buf][_off]);            \
        }                                                                   \
    } while (0)

    f32x4 oacc = {0.f, 0.f, 0.f, 0.f};
    float lpart[4] = {0.f, 0.f, 0.f, 0.f};
    float* outS = out + OFF_S;
    const int r = (wv << 4) + l16;                   // K/V tile row this lane fragments

    STAGE(0, 0);
    for (int t = 0; t < ntiles; ++t) {
        const int p = t & 1;
        __syncthreads();                             // buf[p] staged; prev iter fully done
        if (t + 1 < ntiles) STAGE(1 - p, t + 1);     // overlap next DMA with compute
        const int j0 = t << 6;
        short8 b0 = *reinterpret_cast<const short8*>(&Kb[p][r * 64 + ((quad ^ (r & 7)) << 3)]);
        short8 b1 = *reinterpret_cast<const short8*>(&Kb[p][r * 64 + (((quad + 4) ^ (r & 7)) << 3)]);
        f32x4 c4 = {0.f, 0.f, 0.f, 0.f};
        c4 = __builtin_amdgcn_mfma_f32_16x16x32_bf16(a0, b0, c4, 0, 0, 0);
        c4 = __builtin_amdgcn_mfma_f32_16x16x32_bf16(a1, b1, c4, 0, 0, 0);
        const int j = j0 + r;
        #pragma unroll
        for (int rr = 0; rr < 4; ++rr) {
            const int i = i0 + (quad << 2) + rr;
            float pv = (j <= i) ? __expf(c4[rr] * 0.125f - 8.0f) : 0.0f;
            lpart[rr] += pv;
            Pt[(quad << 2) + rr][r] = f2bf(pv);      // C-layout -> A-layout via LDS
        }
        __syncthreads();
        short8 pa0 = *reinterpret_cast<const short8*>(&Pt[l16][quad << 3]);
        short8 pa1 = *reinterpret_cast<const short8*>(&Pt[l16][32 + (quad << 3)]);
        short8 vb0 = *reinterpret_cast<const short8*>(&Vb[p][r * 64 + ((quad ^ (r & 7)) << 3)]);
        short8 vb1 = *reinterpret_cast<const short8*>(&Vb[p][r * 64 + (((quad + 4) ^ (r & 7)) << 3)]);
        oacc = __builtin_amdgcn_mfma_f32_16x16x32_bf16(pa0, vb0, oacc, 0, 0, 0);
        oacc = __builtin_amdgcn_mfma_f32_16x16x32_bf16(pa1, vb1, oacc, 0, 0, 0);
        // coalesced unnormalized-p store (256B contiguous per 16 lanes)
        const int srow = tid >> 4, scol = (tid & 15) << 2;
        const unsigned short* pp = &Pt[srow][scol];
        float4 pf = { bf2f(pp[0]), bf2f(pp[1]), bf2f(pp[2]), bf2f(pp[3]) };
        *reinterpret_cast<float4*>(outS + (((size_t)(bh * L_ + i0 + srow)) << 11) + j0 + scol) = pf;
    }
    #undef STAGE

    #pragma unroll
    for (int rr = 0; rr < 4; ++rr) {
        float x = lpart[rr];
        x += __shfl_xor(x, 1); x += __shfl_xor(x, 2);
        x += __shfl_xor(x, 4); x += __shfl_xor(x, 8);
        if (l16 == 0) atomicAdd(&l_sums[(quad << 2) + rr], x);
    }
    __syncthreads();
    #pragma unroll
    for (int rr = 0; rr < 4; ++rr) {
        const int i = i0 + (quad << 2) + rr;
        const float inv = 1.0f / l_sums[(quad << 2) + rr];
        out[(((size_t)((b * L_ + i) * H_ + h)) << 6) + (wv << 4) + l16] = oacc[rr] * inv;
    }
    if (tid < 16) ws_inv[(bh << 11) + i0 + tid] = 1.0f / l_sums[tid];
}

// ===== kernel 2: streaming — scale series, write prior + sigma_out =====
__global__ __launch_bounds__(256) void finish(
    const float* __restrict__ sg, const float* __restrict__ ws_inv,
    float* __restrict__ out)
{
    __shared__ float sA[4], sC2[4], sS[4], sI[4];
    const int tid = threadIdx.x;
    const int g0 = blockIdx.x << 2;                  // 4 rows per block, g = bh*2048 + i
    if (tid < 4) {
        const int g = g0 + tid;
        const int bh = g >> 11, i = g & 2047, b = bh >> 3, h = bh & 7;
        const float x = sg[(size_t)((b * L_ + i) * H_ + h)];
        const float sgm = 1.0f / (1.0f + __expf(-5.0f * x)) + 1e-5f;
        const float sp = expm1f(sgm * 1.0986122886681098f);   // 3^sgm - 1
        sS[tid] = sp;
        sA[tid] = 0.3989422804014327f / sp;
        sC2[tid] = 0.5f / (sp * sp);
        sI[tid] = ws_inv[g];
    }
    __syncthreads();
    float* outS = out + OFF_S;
    float* outP = out + OFF_P;
    float* outG = out + OFF_G;
    #pragma unroll
    for (int rr = 0; rr < 4; ++rr) {
        const int g = g0 + rr;
        const int i = g & 2047;
        const size_t base = (size_t)g << 11;
        const float A = sA[rr], C2 = sC2[rr], S = sS[rr], I = sI[rr];
        #pragma unroll
        for (int p = 0; p < 2; ++p) {
            const int c = (tid + (p << 8)) << 2;
            const float d0 = (float)(i - c);
            const float d1 = d0 - 1.f, d2 = d0 - 2.f, d3 = d0 - 3.f;
            float4 pr;
            pr.x = A * __expf(-d0 * d0 * C2);
            pr.y = A * __expf(-d1 * d1 * C2);
            pr.z = A * __expf(-d2 * d2 * C2);
            pr.w = A * __expf(-d3 * d3 * C2);
            *reinterpret_cast<float4*>(outP + base + c) = pr;
            float4 sv = {S, S, S, S};
            *reinterpret_cast<float4*>(outG + base + c) = sv;
            float4 se;
            if (c + 3 <= i) {
                se = *reinterpret_cast<const float4*>(outS + base + c);
                se.x *= I; se.y *= I; se.z *= I; se.w *= I;
            } else if (c > i) {
                se.x = 0.f; se.y = 0.f; se.z = 0.f; se.w = 0.f;
            } else {
                const float4 t4 = *reinterpret_cast<const float4*>(outS + base + c);
                se.x = (c     <= i) ? t4.x * I : 0.f;
                se.y = (c + 1 <= i) ? t4.y * I : 0.f;
                se.z = (c + 2 <= i) ? t4.z * I : 0.f;
                se.w = (c + 3 <= i) ? t4.w * I : 0.f;
            }
            *reinterpret_cast<float4*>(outS + base + c) = se;
        }
    }
}

extern "C" void kernel_launch(void* const* d_in, const int* in_sizes, int n_in,
                              void* d_out, int out_size, void* d_ws, size_t ws_size,
                              hipStream_t stream) {
    const float* q  = (const float*)d_in[0];
    const float* k  = (const float*)d_in[1];
    const float* v  = (const float*)d_in[2];
    const float* sg = (const float*)d_in[3];
    float* outp = (float*)d_out;
    float* ws_inv = (float*)d_ws;
    unsigned short* wsK = (unsigned short*)((char*)d_ws + WS_K);
    unsigned short* wsV = (unsigned short*)((char*)d_ws + WS_V);
    prep<<<dim3(1024), dim3(256), 0, stream>>>(k, v, wsK, wsV);
    attn<<<dim3(2048), dim3(256), 0, stream>>>(q, wsK, wsV, outp, ws_inv);
    finish<<<dim3(8192), dim3(256), 0, stream>>>(sg, ws_inv, outp);
}